// Round 10
// baseline (434.651 us; speedup 1.0000x reference)
//
#include <hip/hip_runtime.h>
#include <hip/hip_bf16.h>

#define NN 50000
#define EE 800000
#define GG 16
#define QD 768
#define NBUCK 196      // ceil(50000/256) dst-buckets of 256 nodes
#define EPB 4000       // edges per block in bin_edges (200 blocks)

typedef __bf16 bf16x8 __attribute__((ext_vector_type(8)));
typedef float f32x4 __attribute__((ext_vector_type(4)));

static __device__ __forceinline__ float bflo(unsigned u) {
    union { unsigned v; float f; } c; c.v = u << 16; return c.f;
}
static __device__ __forceinline__ float bfhi(unsigned u) {
    union { unsigned v; float f; } c; c.v = u & 0xffff0000u; return c.f;
}

// ---------- small prep kernels ----------

__global__ void qkern(const float* __restrict__ qe, const float* __restrict__ W,
                      const float* __restrict__ b, float* __restrict__ q) {
    int g = blockIdx.x, o = threadIdx.x;
    float s = b[o];
    for (int k = 0; k < QD; ++k) s = fmaf(qe[g * QD + k], W[k * 64 + o], s);
    q[g * 64 + o] = fmaxf(s, 0.f);
}

__global__ void convert_x(const float* __restrict__ x, __hip_bfloat16* __restrict__ xb, int n4) {
    int i = blockIdx.x * blockDim.x + threadIdx.x;
    if (i >= n4) return;
    float4 v = ((const float4*)x)[i];
    union { ushort4 u; __hip_bfloat16 h[4]; } o;
    o.h[0] = __float2bfloat16(v.x); o.h[1] = __float2bfloat16(v.y);
    o.h[2] = __float2bfloat16(v.z); o.h[3] = __float2bfloat16(v.w);
    ((ushort4*)xb)[i] = o.u;
}

// W5T[o][k], k in [0,640): k<128 -> root[k][o]; else r=(k-128)>>7, kk=(k-128)&127 -> W[r][kk][o]
__global__ void prep_w5(const float* __restrict__ W, const float* __restrict__ root,
                        __hip_bfloat16* __restrict__ W5T, int O) {
    int idx = blockIdx.x * blockDim.x + threadIdx.x;
    if (idx >= O * 640) return;
    int o = idx / 640, k = idx - o * 640;
    float v;
    if (k < 128) v = root[(size_t)k * O + o];
    else { int r = (k - 128) >> 7, kk = (k - 128) & 127; v = W[((size_t)r * 128 + kk) * O + o]; }
    W5T[idx] = __float2bfloat16(v);
}

// ---------- CSR build: two-level bucket sort ----------
// bucket b = dst >> 8 (256 nodes / bucket). binned entry: (src<<10)|(rel<<8)|(dst&255)

__global__ void bucket_hist(const int* __restrict__ dst, int* __restrict__ bcnt) {
    __shared__ int h[NBUCK];
    int tid = threadIdx.x;
    for (int i = tid; i < NBUCK; i += 256) h[i] = 0;
    __syncthreads();
    for (int e = blockIdx.x * 256 + tid; e < EE; e += gridDim.x * 256)
        atomicAdd(&h[dst[e] >> 8], 1);
    __syncthreads();
    for (int i = tid; i < NBUCK; i += 256) if (h[i]) atomicAdd(&bcnt[i], h[i]);
}

__global__ void bucket_scan(const int* __restrict__ bcnt, int* __restrict__ bbase,
                            int* __restrict__ bcur) {
    __shared__ int wt[4];
    int tid = threadIdx.x, lane = tid & 63, w = tid >> 6;
    int v = (tid < NBUCK) ? bcnt[tid] : 0;
    int sc = v;
#pragma unroll
    for (int off = 1; off < 64; off <<= 1) {
        int t = __shfl_up(sc, off, 64);
        if (lane >= off) sc += t;
    }
    if (lane == 63) wt[w] = sc;
    __syncthreads();
    int wbase = 0;
    for (int ww = 0; ww < w; ++ww) wbase += wt[ww];
    int excl = wbase + sc - v;
    if (tid <= NBUCK) bbase[tid] = excl;   // tid==NBUCK gets total == EE
    if (tid < NBUCK) bcur[tid] = excl;
}

// LDS-ranked binning: each block reserves contiguous runs per bucket -> dense writes
__global__ __launch_bounds__(256) void bin_edges(const int* __restrict__ src,
                                                 const int* __restrict__ dst,
                                                 const int* __restrict__ et,
                                                 int* __restrict__ bcur,
                                                 unsigned* __restrict__ binned) {
    __shared__ int lcnt[NBUCK];
    __shared__ int lbase[NBUCK];
    int tid = threadIdx.x;
    int e0 = blockIdx.x * EPB, e1 = min(e0 + EPB, EE);
    for (int base = e0; base < e1; base += 2048) {
        for (int i = tid; i < NBUCK; i += 256) lcnt[i] = 0;
        __syncthreads();
        unsigned ent[8]; int bk[8], rk[8];
#pragma unroll
        for (int k = 0; k < 8; ++k) {
            int e = base + k * 256 + tid;
            if (e < e1) {
                int d = dst[e];
                bk[k] = d >> 8;
                ent[k] = ((unsigned)src[e] << 10) | ((unsigned)et[e] << 8) | (unsigned)(d & 255);
                rk[k] = atomicAdd(&lcnt[bk[k]], 1);
            } else bk[k] = -1;
        }
        __syncthreads();
        for (int i = tid; i < NBUCK; i += 256)
            lbase[i] = lcnt[i] ? atomicAdd(&bcur[i], lcnt[i]) : 0;
        __syncthreads();
#pragma unroll
        for (int k = 0; k < 8; ++k)
            if (bk[k] >= 0) binned[lbase[bk[k]] + rk[k]] = ent[k];
        __syncthreads();
    }
}

// per-bucket fine CSR: count -> scan -> scatter in LDS; emits csr (rel-sorted per node),
// offsets, and per-(node,rel) counts cnt4
__global__ __launch_bounds__(256) void csr_fine(const int* __restrict__ bbase,
                                                const unsigned* __restrict__ binned,
                                                int* __restrict__ csr,
                                                int* __restrict__ offsets,
                                                int4* __restrict__ cnt4) {
    __shared__ int cnt[1024];   // 256 nodes x 4 rels
    __shared__ int wt[4];
    int b = blockIdx.x, tid = threadIdx.x, lane = tid & 63, w = tid >> 6;
    int seg0 = bbase[b], seg1 = bbase[b + 1];
    for (int i = tid; i < 1024; i += 256) cnt[i] = 0;
    __syncthreads();
    for (int e = seg0 + tid; e < seg1; e += 256) {
        unsigned u = binned[e];
        atomicAdd(&cnt[(u & 255) * 4 + ((u >> 8) & 3)], 1);
    }
    __syncthreads();
    int c0 = cnt[tid * 4], c1 = cnt[tid * 4 + 1], c2 = cnt[tid * 4 + 2], c3 = cnt[tid * 4 + 3];
    int s = c0 + c1 + c2 + c3;
    int sc = s;
#pragma unroll
    for (int off = 1; off < 64; off <<= 1) {
        int t = __shfl_up(sc, off, 64);
        if (lane >= off) sc += t;
    }
    if (lane == 63) wt[w] = sc;
    __syncthreads();
    int wbase = 0;
    for (int ww = 0; ww < w; ++ww) wbase += wt[ww];
    int excl = wbase + sc - s;
    cnt[tid * 4]     = excl;
    cnt[tid * 4 + 1] = excl + c0;
    cnt[tid * 4 + 2] = excl + c0 + c1;
    cnt[tid * 4 + 3] = excl + c0 + c1 + c2;
    int node = b * 256 + tid;
    if (node < NN) {
        offsets[node] = seg0 + excl;
        cnt4[node] = make_int4(c0, c1, c2, c3);
    }
    if (b == NBUCK - 1 && tid == 0) offsets[NN] = EE;
    __syncthreads();
    for (int e = seg0 + tid; e < seg1; e += 256) {
        unsigned u = binned[e];
        int r = atomicAdd(&cnt[(u & 255) * 4 + ((u >> 8) & 3)], 1);
        csr[seg0 + r] = (int)(((u >> 10) << 2) | ((u >> 8) & 3));   // (src<<2)|rel
    }
}

// ---------- agg_x: input-space aggregation via boundary snapshots ----------
// CSR is rel-sorted per node, so rel identity == position vs boundaries b1,b2,b3.
// Keep ONE running sum (2 adds/edge); snapshot it when the (uniform) edge index
// crosses a boundary (scalar cmp, branch taken <=3x/node); per-rel sums by
// subtraction (exact partial sums, fp32). 8 loads in flight.

__global__ __launch_bounds__(256) void agg_x(const __hip_bfloat16* __restrict__ X,
                                             const int* __restrict__ offsets,
                                             const int4* __restrict__ cnt4,
                                             const int* __restrict__ csr,
                                             __hip_bfloat16* __restrict__ X5agg) {
    int node = blockIdx.x * 4 + (threadIdx.x >> 6);
    int lane = threadIdx.x & 63;
    const char* xb = (const char*)X;
    int e0 = offsets[node];
    int4 c4 = cnt4[node];
    int b1 = c4.x, b2 = b1 + c4.y, b3 = b2 + c4.z;
    int tot = b3 + c4.w;
    float aL = 0.f, aH = 0.f;             // running sum (lo/hi col halves)
    float s1L = 0.f, s1H = 0.f, s2L = 0.f, s2H = 0.f, s3L = 0.f, s3H = 0.f;
    for (int base = 0; base < tot; base += 64) {
        int i = base + lane;
        int packed = (i < tot) ? csr[e0 + i] : 0;
        int m = min(64, tot - base);
        int j = 0;
        for (; j + 8 <= m; j += 8) {
            int p[8]; unsigned u[8];
#pragma unroll
            for (int k = 0; k < 8; ++k)
                p[k] = __builtin_amdgcn_readlane(packed, j + k);
#pragma unroll
            for (int k = 0; k < 8; ++k)
                u[k] = *(const unsigned*)(xb + (size_t)(p[k] >> 2) * 256 + lane * 4);
#pragma unroll
            for (int k = 0; k < 8; ++k) {
                int g = base + j + k;            // uniform -> scalar compares
                if (g == b1) { s1L = aL; s1H = aH; }
                if (g == b2) { s2L = aL; s2H = aH; }
                if (g == b3) { s3L = aL; s3H = aH; }
                aL += bflo(u[k]); aH += bfhi(u[k]);
            }
        }
        for (; j < m; ++j) {
            int p = __builtin_amdgcn_readlane(packed, j);
            unsigned u = *(const unsigned*)(xb + (size_t)(p >> 2) * 256 + lane * 4);
            int g = base + j;
            if (g == b1) { s1L = aL; s1H = aH; }
            if (g == b2) { s2L = aL; s2H = aH; }
            if (g == b3) { s3L = aL; s3H = aH; }
            aL += bflo(u); aH += bfhi(u);
        }
    }
    if (b1 == tot) { s1L = aL; s1H = aH; }
    if (b2 == tot) { s2L = aL; s2H = aH; }
    if (b3 == tot) { s3L = aL; s3H = aH; }
    float iv0 = 1.f / fmaxf((float)c4.x, 1.f);
    float iv1 = 1.f / fmaxf((float)c4.y, 1.f);
    float iv2 = 1.f / fmaxf((float)c4.z, 1.f);
    float iv3 = 1.f / fmaxf((float)c4.w, 1.f);
    float rL[4], rH[4], iv[4] = {iv0, iv1, iv2, iv3};
    rL[0] = s1L;       rH[0] = s1H;
    rL[1] = s2L - s1L; rH[1] = s2H - s1H;
    rL[2] = s3L - s2L; rH[2] = s3H - s2H;
    rL[3] = aL  - s3L; rH[3] = aH  - s3H;
    char* x5 = (char*)X5agg;
#pragma unroll
    for (int r = 0; r < 4; ++r) {
        __hip_bfloat16 g0 = __float2bfloat16(rL[r] * iv[r]);
        __hip_bfloat16 g1 = __float2bfloat16(rH[r] * iv[r]);
        ushort2 pk;
        pk.x = *(unsigned short*)&g0; pk.y = *(unsigned short*)&g1;
        *(ushort2*)(x5 + (size_t)node * 1024 + r * 256 + lane * 4) = pk;
    }
}

// ---------- dense5: out[N][O] = [Xself | X5agg] @ W5T^T + bias, fused epilogue ----------
// MODE 0: O=64, relu, write bf16 [h | q[batch]] (128 cols). MODE 1: O=128, relu bf16.
// MODE 2: O=64, no relu, fp32 to out.
// K=640: k<128 from Xself (layer input), k>=128 from X5agg. B staged per 64-k
// chunk in LDS in MFMA-fragment order (16B/lane ds_read_b128).

template <int O, int MODE>
__global__ __launch_bounds__(256) void dense5(const __hip_bfloat16* __restrict__ Xself,
                                              const __hip_bfloat16* __restrict__ X5agg,
                                              const __hip_bfloat16* __restrict__ W5T,
                                              const float* __restrict__ bias,
                                              const float* __restrict__ q,
                                              const int* __restrict__ batch,
                                              __hip_bfloat16* __restrict__ xnext,
                                              float* __restrict__ out) {
    __shared__ char lds[16384];
    constexpr int NCT = O / 16;
    int tid = threadIdx.x;
    int wave = tid >> 6, lane = tid & 63;
    int quad = lane >> 4, l15 = lane & 15;
    int mbase = blockIdx.x * 128 + wave * 32;
    const __bf16* Ws = (const __bf16*)W5T;

    f32x4 acc[2][NCT];
#pragma unroll
    for (int mt = 0; mt < 2; ++mt)
#pragma unroll
        for (int t = 0; t < NCT; ++t) acc[mt][t] = f32x4{0, 0, 0, 0};

    int arow0 = min(mbase + l15, NN - 1);
    int arow1 = min(mbase + 16 + l15, NN - 1);
    const __bf16* aps0 = (const __bf16*)Xself + (size_t)arow0 * 128;
    const __bf16* aps1 = (const __bf16*)Xself + (size_t)arow1 * 128;
    const __bf16* apg0 = (const __bf16*)X5agg + (size_t)arow0 * 512;
    const __bf16* apg1 = (const __bf16*)X5agg + (size_t)arow1 * 512;

    for (int kc = 0; kc < 10; ++kc) {
        int k0 = kc * 64;
        const __bf16* a0base = (kc < 2) ? aps0 + kc * 64 : apg0 + (kc - 2) * 64;
        const __bf16* a1base = (kc < 2) ? aps1 + kc * 64 : apg1 + (kc - 2) * 64;
        __syncthreads();
        constexpr int NF = NCT * 2 * 64;     // fragments per chunk (512 / 1024)
#pragma unroll
        for (int i = 0; i < NF / 256; ++i) {
            int f = tid + i * 256;
            int fl = f & 63;
            int o = (f >> 7) * 16 + (fl & 15);
            int kk = k0 + ((f >> 6) & 1) * 32 + ((fl >> 4) & 3) * 8;
            *(uint4*)(lds + f * 16) = *(const uint4*)(Ws + (size_t)o * 640 + kk);
        }
        __syncthreads();
#pragma unroll
        for (int ks = 0; ks < 2; ++ks) {
            bf16x8 a0 = *(const bf16x8*)(a0base + ks * 32 + quad * 8);
            bf16x8 a1 = *(const bf16x8*)(a1base + ks * 32 + quad * 8);
#pragma unroll
            for (int t = 0; t < NCT; ++t) {
                bf16x8 b = *(const bf16x8*)(lds + ((t * 2 + ks) * 64 + lane) * 16);
                acc[0][t] = __builtin_amdgcn_mfma_f32_16x16x32_bf16(a0, b, acc[0][t], 0, 0, 0);
                acc[1][t] = __builtin_amdgcn_mfma_f32_16x16x32_bf16(a1, b, acc[1][t], 0, 0, 0);
            }
        }
    }
    __syncthreads();

    if (MODE == 2) {
#pragma unroll
        for (int mt = 0; mt < 2; ++mt)
#pragma unroll
            for (int t = 0; t < NCT; ++t) {
                int col = t * 16 + l15;
                float bv = bias[col];
#pragma unroll
                for (int reg = 0; reg < 4; ++reg) {
                    int row = mbase + mt * 16 + quad * 4 + reg;
                    if (row < NN) out[(size_t)row * 64 + col] = acc[mt][t][reg] + bv;
                }
            }
        return;
    }

    // bf16 path: per-wave LDS tile [16][128], one row-tile at a time
    __hip_bfloat16* tp = (__hip_bfloat16*)(lds + wave * 4096);
#pragma unroll
    for (int mt = 0; mt < 2; ++mt) {
        int m0 = mbase + mt * 16;
#pragma unroll
        for (int t = 0; t < NCT; ++t) {
            int col = t * 16 + l15;
            float bv = bias[col];
#pragma unroll
            for (int reg = 0; reg < 4; ++reg)
                tp[(quad * 4 + reg) * 128 + col] =
                    __float2bfloat16(fmaxf(acc[mt][t][reg] + bv, 0.f));
        }
        if (MODE == 0) {
            // fill q columns 64..127: lane -> row=lane>>2, colseg=(lane&3)*16
            int row = lane >> 2;
            int cs = (lane & 3) * 16;
            int rnode = min(m0 + row, NN - 1);
            int g = batch[rnode];
#pragma unroll
            for (int i = 0; i < 4; ++i) {
                float4 v = *(const float4*)(q + g * 64 + cs + i * 4);
                __hip_bfloat16 q0 = __float2bfloat16(v.x), q1 = __float2bfloat16(v.y);
                __hip_bfloat16 q2 = __float2bfloat16(v.z), q3 = __float2bfloat16(v.w);
                ushort4 pk;
                pk.x = *(unsigned short*)&q0; pk.y = *(unsigned short*)&q1;
                pk.z = *(unsigned short*)&q2; pk.w = *(unsigned short*)&q3;
                *(ushort4*)(tp + row * 128 + 64 + cs + i * 4) = pk;
            }
        }
        // store 16 rows x 256 B, 16B/lane coalesced (DS ops in-order per wave)
#pragma unroll
        for (int p = 0; p < 4; ++p) {
            int c = p * 64 + lane;
            int row = m0 + (c >> 4);
            if (row < NN)
                *(uint4*)((char*)xnext + (size_t)row * 256 + (c & 15) * 16) =
                    *(const uint4*)((const char*)tp + c * 16);
        }
    }
}

// ---------- launch ----------

static inline size_t rup(size_t x) { return (x + 255) & ~(size_t)255; }

extern "C" void kernel_launch(void* const* d_in, const int* in_sizes, int n_in,
                              void* d_out, int out_size, void* d_ws, size_t ws_size,
                              hipStream_t stream) {
    const float* x      = (const float*)d_in[0];
    const int*   esrc   = (const int*)d_in[1];
    const int*   edst   = esrc + EE;
    const int*   eattr  = (const int*)d_in[2];
    const int*   batch  = (const int*)d_in[3];
    const float* qe     = (const float*)d_in[4];
    const float* qn_W   = (const float*)d_in[5];
    const float* qn_b   = (const float*)d_in[6];
    const float* W0 = (const float*)d_in[7],  *root0 = (const float*)d_in[8],  *b0 = (const float*)d_in[9];
    const float* W1 = (const float*)d_in[10], *root1 = (const float*)d_in[11], *b1 = (const float*)d_in[12];
    const float* W2 = (const float*)d_in[13], *root2 = (const float*)d_in[14], *b2 = (const float*)d_in[15];
    const float* W3 = (const float*)d_in[16], *root3 = (const float*)d_in[17], *b3 = (const float*)d_in[18];
    float* out = (float*)d_out;

    char* w = (char*)d_ws;
    float* q       = (float*)w;  w += rup(GG * 64 * 4);
    int*   offsets = (int*)w;    w += rup(((size_t)NN + 1) * 4);
    int4*  cnt4    = (int4*)w;   w += rup((size_t)NN * 16);
    int*   bcnt    = (int*)w;    w += rup((size_t)NBUCK * 4);
    int*   bbase   = (int*)w;    w += rup(((size_t)NBUCK + 1) * 4);
    int*   bcur    = (int*)w;    w += rup((size_t)NBUCK * 4);
    unsigned* binned = (unsigned*)w; w += rup((size_t)EE * 4);
    int*   csr     = (int*)w;    w += rup((size_t)EE * 4);
    __hip_bfloat16* W5T0 = (__hip_bfloat16*)w; w += rup((size_t)64 * 640 * 2);
    __hip_bfloat16* W5T1 = (__hip_bfloat16*)w; w += rup((size_t)128 * 640 * 2);
    __hip_bfloat16* W5T2 = (__hip_bfloat16*)w; w += rup((size_t)128 * 640 * 2);
    __hip_bfloat16* W5T3 = (__hip_bfloat16*)w; w += rup((size_t)64 * 640 * 2);
    __hip_bfloat16* xb0 = (__hip_bfloat16*)w;  w += rup((size_t)NN * 128 * 2);
    __hip_bfloat16* xb1 = (__hip_bfloat16*)w;  w += rup((size_t)NN * 128 * 2);
    __hip_bfloat16* X5  = (__hip_bfloat16*)w;  w += rup((size_t)NN * 512 * 2);

    hipMemsetAsync(bcnt, 0, (size_t)NBUCK * 4, stream);

    // question projection + input conversion + weight prep
    qkern<<<GG, 64, 0, stream>>>(qe, qn_W, qn_b, q);
    convert_x<<<(NN * 128 / 4 + 255) / 256, 256, 0, stream>>>(x, xb0, NN * 128 / 4);
    prep_w5<<<(64 * 640 + 255) / 256, 256, 0, stream>>>(W0, root0, W5T0, 64);
    prep_w5<<<(128 * 640 + 255) / 256, 256, 0, stream>>>(W1, root1, W5T1, 128);
    prep_w5<<<(128 * 640 + 255) / 256, 256, 0, stream>>>(W2, root2, W5T2, 128);
    prep_w5<<<(64 * 640 + 255) / 256, 256, 0, stream>>>(W3, root3, W5T3, 64);

    // CSR build: bucket sort
    bucket_hist<<<256, 256, 0, stream>>>(edst, bcnt);
    bucket_scan<<<1, 256, 0, stream>>>(bcnt, bbase, bcur);
    bin_edges<<<(EE + EPB - 1) / EPB, 256, 0, stream>>>(esrc, edst, eattr, bcur, binned);
    csr_fine<<<NBUCK, 256, 0, stream>>>(bbase, binned, csr, offsets, cnt4);

    int aggblk = NN / 4;                   // 12500
    int dblk = (NN + 127) / 128;           // 391

    // layer 0: xb0 -> X5 -> [h|q] xb1
    agg_x<<<aggblk, 256, 0, stream>>>(xb0, offsets, cnt4, csr, X5);
    dense5<64, 0><<<dblk, 256, 0, stream>>>(xb0, X5, W5T0, b0, q, batch, xb1, nullptr);

    // layer 1: xb1 -> X5 -> xb0
    agg_x<<<aggblk, 256, 0, stream>>>(xb1, offsets, cnt4, csr, X5);
    dense5<128, 1><<<dblk, 256, 0, stream>>>(xb1, X5, W5T1, b1, nullptr, nullptr, xb0, nullptr);

    // layer 2: xb0 -> X5 -> xb1
    agg_x<<<aggblk, 256, 0, stream>>>(xb0, offsets, cnt4, csr, X5);
    dense5<128, 1><<<dblk, 256, 0, stream>>>(xb0, X5, W5T2, b2, nullptr, nullptr, xb1, nullptr);

    // layer 3: xb1 -> X5 -> fp32 out
    agg_x<<<aggblk, 256, 0, stream>>>(xb1, offsets, cnt4, csr, X5);
    dense5<64, 2><<<dblk, 256, 0, stream>>>(xb1, X5, W5T3, b3, nullptr, nullptr, nullptr, out);
}

// Round 11
// 419.541 us; speedup vs baseline: 1.0360x; 1.0360x over previous
//
#include <hip/hip_runtime.h>
#include <hip/hip_bf16.h>

#define NN 50000
#define EE 800000
#define GG 16
#define QD 768
#define NBUCK 196      // ceil(50000/256) dst-buckets of 256 nodes
#define EPB 4000       // edges per block in bin_edges (200 blocks)

typedef __bf16 bf16x8 __attribute__((ext_vector_type(8)));
typedef float f32x4 __attribute__((ext_vector_type(4)));

static __device__ __forceinline__ float bflo(unsigned u) {
    union { unsigned v; float f; } c; c.v = u << 16; return c.f;
}
static __device__ __forceinline__ float bfhi(unsigned u) {
    union { unsigned v; float f; } c; c.v = u & 0xffff0000u; return c.f;
}

// ---------- fused prep: convert_x + 4x prep_w5 + qkern, range-dispatched ----------
// W5T[o][k], k in [0,640): k<128 -> root[k][o]; else r=(k-128)>>7 -> W[r][(k-128)&127][o]

#define PB_CVT 6250                 // NN*128/4 / 256
#define PB_W0  (PB_CVT + 160)       // 64*640/256
#define PB_W1  (PB_W0 + 320)       // 128*640/256
#define PB_W2  (PB_W1 + 320)
#define PB_W3  (PB_W2 + 160)
#define PB_Q   (PB_W3 + 4)          // 16 graphs / 4 waves

__global__ __launch_bounds__(256) void prep_all(
        const float* __restrict__ x, __hip_bfloat16* __restrict__ xb,
        const float* __restrict__ qe, const float* __restrict__ qn_W,
        const float* __restrict__ qn_b, float* __restrict__ q,
        const float* __restrict__ W0, const float* __restrict__ root0, __hip_bfloat16* __restrict__ W5T0,
        const float* __restrict__ W1, const float* __restrict__ root1, __hip_bfloat16* __restrict__ W5T1,
        const float* __restrict__ W2, const float* __restrict__ root2, __hip_bfloat16* __restrict__ W5T2,
        const float* __restrict__ W3, const float* __restrict__ root3, __hip_bfloat16* __restrict__ W5T3) {
    int blk = blockIdx.x, tid = threadIdx.x;
    if (blk < PB_CVT) {
        int i = blk * 256 + tid;              // float4 index
        float4 v = ((const float4*)x)[i];
        union { ushort4 u; __hip_bfloat16 h[4]; } o;
        o.h[0] = __float2bfloat16(v.x); o.h[1] = __float2bfloat16(v.y);
        o.h[2] = __float2bfloat16(v.z); o.h[3] = __float2bfloat16(v.w);
        ((ushort4*)xb)[i] = o.u;
    } else if (blk < PB_W3) {
        const float* W; const float* root; __hip_bfloat16* WT; int O, base;
        if (blk < PB_W0)      { W = W0; root = root0; WT = W5T0; O = 64;  base = PB_CVT; }
        else if (blk < PB_W1) { W = W1; root = root1; WT = W5T1; O = 128; base = PB_W0; }
        else if (blk < PB_W2) { W = W2; root = root2; WT = W5T2; O = 128; base = PB_W1; }
        else                  { W = W3; root = root3; WT = W5T3; O = 64;  base = PB_W2; }
        int idx = (blk - base) * 256 + tid;
        int o = idx / 640, k = idx - o * 640;
        float v;
        if (k < 128) v = root[(size_t)k * O + o];
        else { int r = (k - 128) >> 7, kk = (k - 128) & 127; v = W[((size_t)r * 128 + kk) * O + o]; }
        WT[idx] = __float2bfloat16(v);
    } else {
        int g = (blk - PB_W3) * 4 + (tid >> 6);
        int o = tid & 63;
        float s = qn_b[o];
        for (int k = 0; k < QD; ++k) s = fmaf(qe[g * QD + k], qn_W[k * 64 + o], s);
        q[g * 64 + o] = fmaxf(s, 0.f);
    }
}

// ---------- CSR build: two-level bucket sort ----------
// bucket b = dst >> 8 (256 nodes / bucket). binned entry: (src<<10)|(rel<<8)|(dst&255)

__global__ void bucket_hist(const int* __restrict__ dst, int* __restrict__ bcnt) {
    __shared__ int h[NBUCK];
    int tid = threadIdx.x;
    for (int i = tid; i < NBUCK; i += 256) h[i] = 0;
    __syncthreads();
    for (int e = blockIdx.x * 256 + tid; e < EE; e += gridDim.x * 256)
        atomicAdd(&h[dst[e] >> 8], 1);
    __syncthreads();
    for (int i = tid; i < NBUCK; i += 256) if (h[i]) atomicAdd(&bcnt[i], h[i]);
}

__global__ void bucket_scan(const int* __restrict__ bcnt, int* __restrict__ bbase,
                            int* __restrict__ bcur) {
    __shared__ int wt[4];
    int tid = threadIdx.x, lane = tid & 63, w = tid >> 6;
    int v = (tid < NBUCK) ? bcnt[tid] : 0;
    int sc = v;
#pragma unroll
    for (int off = 1; off < 64; off <<= 1) {
        int t = __shfl_up(sc, off, 64);
        if (lane >= off) sc += t;
    }
    if (lane == 63) wt[w] = sc;
    __syncthreads();
    int wbase = 0;
    for (int ww = 0; ww < w; ++ww) wbase += wt[ww];
    int excl = wbase + sc - v;
    if (tid <= NBUCK) bbase[tid] = excl;   // tid==NBUCK gets total == EE
    if (tid < NBUCK) bcur[tid] = excl;
}

// LDS-ranked binning: each block reserves contiguous runs per bucket -> dense writes
__global__ __launch_bounds__(256) void bin_edges(const int* __restrict__ src,
                                                 const int* __restrict__ dst,
                                                 const int* __restrict__ et,
                                                 int* __restrict__ bcur,
                                                 unsigned* __restrict__ binned) {
    __shared__ int lcnt[NBUCK];
    __shared__ int lbase[NBUCK];
    int tid = threadIdx.x;
    int e0 = blockIdx.x * EPB, e1 = min(e0 + EPB, EE);
    for (int base = e0; base < e1; base += 2048) {
        for (int i = tid; i < NBUCK; i += 256) lcnt[i] = 0;
        __syncthreads();
        unsigned ent[8]; int bk[8], rk[8];
#pragma unroll
        for (int k = 0; k < 8; ++k) {
            int e = base + k * 256 + tid;
            if (e < e1) {
                int d = dst[e];
                bk[k] = d >> 8;
                ent[k] = ((unsigned)src[e] << 10) | ((unsigned)et[e] << 8) | (unsigned)(d & 255);
                rk[k] = atomicAdd(&lcnt[bk[k]], 1);
            } else bk[k] = -1;
        }
        __syncthreads();
        for (int i = tid; i < NBUCK; i += 256)
            lbase[i] = lcnt[i] ? atomicAdd(&bcur[i], lcnt[i]) : 0;
        __syncthreads();
#pragma unroll
        for (int k = 0; k < 8; ++k)
            if (bk[k] >= 0) binned[lbase[bk[k]] + rk[k]] = ent[k];
        __syncthreads();
    }
}

// per-bucket fine CSR: count -> scan -> scatter in LDS; emits csr (rel-sorted per node),
// offsets, and per-(node,rel) counts cnt4
__global__ __launch_bounds__(256) void csr_fine(const int* __restrict__ bbase,
                                                const unsigned* __restrict__ binned,
                                                int* __restrict__ csr,
                                                int* __restrict__ offsets,
                                                int4* __restrict__ cnt4) {
    __shared__ int cnt[1024];   // 256 nodes x 4 rels
    __shared__ int wt[4];
    int b = blockIdx.x, tid = threadIdx.x, lane = tid & 63, w = tid >> 6;
    int seg0 = bbase[b], seg1 = bbase[b + 1];
    for (int i = tid; i < 1024; i += 256) cnt[i] = 0;
    __syncthreads();
    for (int e = seg0 + tid; e < seg1; e += 256) {
        unsigned u = binned[e];
        atomicAdd(&cnt[(u & 255) * 4 + ((u >> 8) & 3)], 1);
    }
    __syncthreads();
    int c0 = cnt[tid * 4], c1 = cnt[tid * 4 + 1], c2 = cnt[tid * 4 + 2], c3 = cnt[tid * 4 + 3];
    int s = c0 + c1 + c2 + c3;
    int sc = s;
#pragma unroll
    for (int off = 1; off < 64; off <<= 1) {
        int t = __shfl_up(sc, off, 64);
        if (lane >= off) sc += t;
    }
    if (lane == 63) wt[w] = sc;
    __syncthreads();
    int wbase = 0;
    for (int ww = 0; ww < w; ++ww) wbase += wt[ww];
    int excl = wbase + sc - s;
    cnt[tid * 4]     = excl;
    cnt[tid * 4 + 1] = excl + c0;
    cnt[tid * 4 + 2] = excl + c0 + c1;
    cnt[tid * 4 + 3] = excl + c0 + c1 + c2;
    int node = b * 256 + tid;
    if (node < NN) {
        offsets[node] = seg0 + excl;
        cnt4[node] = make_int4(c0, c1, c2, c3);
    }
    if (b == NBUCK - 1 && tid == 0) offsets[NN] = EE;
    __syncthreads();
    for (int e = seg0 + tid; e < seg1; e += 256) {
        unsigned u = binned[e];
        int r = atomicAdd(&cnt[(u & 255) * 4 + ((u >> 8) & 3)], 1);
        csr[seg0 + r] = (int)(((u >> 10) << 2) | ((u >> 8) & 3));   // (src<<2)|rel
    }
}

// ---------- agg_x: input-space aggregation (R8 form — best measured) ----------
// X5agg[node] = [ mean_r0 (128) | mean_r1 | mean_r2 | mean_r3 ]  bf16 (512 cols)
// One wave per node, unified pass over the node's edges, 8 gathers in flight;
// rel from readlane is wave-uniform -> scalar branch into 4 acc pairs.

__global__ __launch_bounds__(256) void agg_x(const __hip_bfloat16* __restrict__ X,
                                             const int* __restrict__ offsets,
                                             const int4* __restrict__ cnt4,
                                             const int* __restrict__ csr,
                                             __hip_bfloat16* __restrict__ X5agg) {
    int node = blockIdx.x * 4 + (threadIdx.x >> 6);
    int lane = threadIdx.x & 63;
    const char* xb = (const char*)X;
    int e0 = offsets[node];
    int4 c4 = cnt4[node];
    int tot = c4.x + c4.y + c4.z + c4.w;
    float a0 = 0.f, a1 = 0.f, a2 = 0.f, a3 = 0.f;   // lo halves per rel
    float h0 = 0.f, h1 = 0.f, h2 = 0.f, h3 = 0.f;   // hi halves per rel
    for (int base = 0; base < tot; base += 64) {
        int i = base + lane;
        int packed = (i < tot) ? csr[e0 + i] : 0;
        int m = min(64, tot - base);
        int j = 0;
        for (; j + 8 <= m; j += 8) {
            int p[8]; unsigned u[8];
#pragma unroll
            for (int k = 0; k < 8; ++k)
                p[k] = __builtin_amdgcn_readlane(packed, j + k);
#pragma unroll
            for (int k = 0; k < 8; ++k)
                u[k] = *(const unsigned*)(xb + (size_t)(p[k] >> 2) * 256 + lane * 4);
#pragma unroll
            for (int k = 0; k < 8; ++k) {
                int r = p[k] & 3;
                float lo = bflo(u[k]), hi = bfhi(u[k]);
                if (r == 0)      { a0 += lo; h0 += hi; }
                else if (r == 1) { a1 += lo; h1 += hi; }
                else if (r == 2) { a2 += lo; h2 += hi; }
                else             { a3 += lo; h3 += hi; }
            }
        }
        for (; j < m; ++j) {
            int p = __builtin_amdgcn_readlane(packed, j);
            unsigned u = *(const unsigned*)(xb + (size_t)(p >> 2) * 256 + lane * 4);
            int r = p & 3;
            float lo = bflo(u), hi = bfhi(u);
            if (r == 0)      { a0 += lo; h0 += hi; }
            else if (r == 1) { a1 += lo; h1 += hi; }
            else if (r == 2) { a2 += lo; h2 += hi; }
            else             { a3 += lo; h3 += hi; }
        }
    }
    char* x5 = (char*)X5agg;
    float iv0 = 1.f / fmaxf((float)c4.x, 1.f);
    float iv1 = 1.f / fmaxf((float)c4.y, 1.f);
    float iv2 = 1.f / fmaxf((float)c4.z, 1.f);
    float iv3 = 1.f / fmaxf((float)c4.w, 1.f);
#pragma unroll
    for (int r = 0; r < 4; ++r) {
        float lo = (r == 0) ? a0 : (r == 1) ? a1 : (r == 2) ? a2 : a3;
        float hi = (r == 0) ? h0 : (r == 1) ? h1 : (r == 2) ? h2 : h3;
        float iv = (r == 0) ? iv0 : (r == 1) ? iv1 : (r == 2) ? iv2 : iv3;
        __hip_bfloat16 g0 = __float2bfloat16(lo * iv), g1 = __float2bfloat16(hi * iv);
        ushort2 pk;
        pk.x = *(unsigned short*)&g0; pk.y = *(unsigned short*)&g1;
        *(ushort2*)(x5 + (size_t)node * 1024 + r * 256 + lane * 4) = pk;
    }
}

// ---------- dense5: out[N][O] = [Xself | X5agg] @ W5T^T + bias, fused epilogue ----------
// MODE 0: O=64, relu, write bf16 [h | q[batch]] (128 cols). MODE 1: O=128, relu bf16.
// MODE 2: O=64, no relu, fp32 to out.

template <int O, int MODE>
__global__ __launch_bounds__(256) void dense5(const __hip_bfloat16* __restrict__ Xself,
                                              const __hip_bfloat16* __restrict__ X5agg,
                                              const __hip_bfloat16* __restrict__ W5T,
                                              const float* __restrict__ bias,
                                              const float* __restrict__ q,
                                              const int* __restrict__ batch,
                                              __hip_bfloat16* __restrict__ xnext,
                                              float* __restrict__ out) {
    __shared__ char lds[16384];
    constexpr int NCT = O / 16;
    int tid = threadIdx.x;
    int wave = tid >> 6, lane = tid & 63;
    int quad = lane >> 4, l15 = lane & 15;
    int mbase = blockIdx.x * 128 + wave * 32;
    const __bf16* Ws = (const __bf16*)W5T;

    f32x4 acc[2][NCT];
#pragma unroll
    for (int mt = 0; mt < 2; ++mt)
#pragma unroll
        for (int t = 0; t < NCT; ++t) acc[mt][t] = f32x4{0, 0, 0, 0};

    int arow0 = min(mbase + l15, NN - 1);
    int arow1 = min(mbase + 16 + l15, NN - 1);
    const __bf16* aps0 = (const __bf16*)Xself + (size_t)arow0 * 128;
    const __bf16* aps1 = (const __bf16*)Xself + (size_t)arow1 * 128;
    const __bf16* apg0 = (const __bf16*)X5agg + (size_t)arow0 * 512;
    const __bf16* apg1 = (const __bf16*)X5agg + (size_t)arow1 * 512;

    for (int kc = 0; kc < 10; ++kc) {
        int k0 = kc * 64;
        const __bf16* a0base = (kc < 2) ? aps0 + kc * 64 : apg0 + (kc - 2) * 64;
        const __bf16* a1base = (kc < 2) ? aps1 + kc * 64 : apg1 + (kc - 2) * 64;
        __syncthreads();
        constexpr int NF = NCT * 2 * 64;     // fragments per chunk (512 / 1024)
#pragma unroll
        for (int i = 0; i < NF / 256; ++i) {
            int f = tid + i * 256;
            int fl = f & 63;
            int o = (f >> 7) * 16 + (fl & 15);
            int kk = k0 + ((f >> 6) & 1) * 32 + ((fl >> 4) & 3) * 8;
            *(uint4*)(lds + f * 16) = *(const uint4*)(Ws + (size_t)o * 640 + kk);
        }
        __syncthreads();
#pragma unroll
        for (int ks = 0; ks < 2; ++ks) {
            bf16x8 a0 = *(const bf16x8*)(a0base + ks * 32 + quad * 8);
            bf16x8 a1 = *(const bf16x8*)(a1base + ks * 32 + quad * 8);
#pragma unroll
            for (int t = 0; t < NCT; ++t) {
                bf16x8 b = *(const bf16x8*)(lds + ((t * 2 + ks) * 64 + lane) * 16);
                acc[0][t] = __builtin_amdgcn_mfma_f32_16x16x32_bf16(a0, b, acc[0][t], 0, 0, 0);
                acc[1][t] = __builtin_amdgcn_mfma_f32_16x16x32_bf16(a1, b, acc[1][t], 0, 0, 0);
            }
        }
    }
    __syncthreads();

    if (MODE == 2) {
#pragma unroll
        for (int mt = 0; mt < 2; ++mt)
#pragma unroll
            for (int t = 0; t < NCT; ++t) {
                int col = t * 16 + l15;
                float bv = bias[col];
#pragma unroll
                for (int reg = 0; reg < 4; ++reg) {
                    int row = mbase + mt * 16 + quad * 4 + reg;
                    if (row < NN) out[(size_t)row * 64 + col] = acc[mt][t][reg] + bv;
                }
            }
        return;
    }

    // bf16 path: per-wave LDS tile [16][128], one row-tile at a time
    __hip_bfloat16* tp = (__hip_bfloat16*)(lds + wave * 4096);
#pragma unroll
    for (int mt = 0; mt < 2; ++mt) {
        int m0 = mbase + mt * 16;
#pragma unroll
        for (int t = 0; t < NCT; ++t) {
            int col = t * 16 + l15;
            float bv = bias[col];
#pragma unroll
            for (int reg = 0; reg < 4; ++reg)
                tp[(quad * 4 + reg) * 128 + col] =
                    __float2bfloat16(fmaxf(acc[mt][t][reg] + bv, 0.f));
        }
        if (MODE == 0) {
            // fill q columns 64..127: lane -> row=lane>>2, colseg=(lane&3)*16
            int row = lane >> 2;
            int cs = (lane & 3) * 16;
            int rnode = min(m0 + row, NN - 1);
            int g = batch[rnode];
#pragma unroll
            for (int i = 0; i < 4; ++i) {
                float4 v = *(const float4*)(q + g * 64 + cs + i * 4);
                __hip_bfloat16 q0 = __float2bfloat16(v.x), q1 = __float2bfloat16(v.y);
                __hip_bfloat16 q2 = __float2bfloat16(v.z), q3 = __float2bfloat16(v.w);
                ushort4 pk;
                pk.x = *(unsigned short*)&q0; pk.y = *(unsigned short*)&q1;
                pk.z = *(unsigned short*)&q2; pk.w = *(unsigned short*)&q3;
                *(ushort4*)(tp + row * 128 + 64 + cs + i * 4) = pk;
            }
        }
        // store 16 rows x 256 B, 16B/lane coalesced
#pragma unroll
        for (int p = 0; p < 4; ++p) {
            int c = p * 64 + lane;
            int row = m0 + (c >> 4);
            if (row < NN)
                *(uint4*)((char*)xnext + (size_t)row * 256 + (c & 15) * 16) =
                    *(const uint4*)((const char*)tp + c * 16);
        }
    }
}

// ---------- launch ----------

static inline size_t rup(size_t x) { return (x + 255) & ~(size_t)255; }

extern "C" void kernel_launch(void* const* d_in, const int* in_sizes, int n_in,
                              void* d_out, int out_size, void* d_ws, size_t ws_size,
                              hipStream_t stream) {
    const float* x      = (const float*)d_in[0];
    const int*   esrc   = (const int*)d_in[1];
    const int*   edst   = esrc + EE;
    const int*   eattr  = (const int*)d_in[2];
    const int*   batch  = (const int*)d_in[3];
    const float* qe     = (const float*)d_in[4];
    const float* qn_W   = (const float*)d_in[5];
    const float* qn_b   = (const float*)d_in[6];
    const float* W0 = (const float*)d_in[7],  *root0 = (const float*)d_in[8],  *b0 = (const float*)d_in[9];
    const float* W1 = (const float*)d_in[10], *root1 = (const float*)d_in[11], *b1 = (const float*)d_in[12];
    const float* W2 = (const float*)d_in[13], *root2 = (const float*)d_in[14], *b2 = (const float*)d_in[15];
    const float* W3 = (const float*)d_in[16], *root3 = (const float*)d_in[17], *b3 = (const float*)d_in[18];
    float* out = (float*)d_out;

    char* w = (char*)d_ws;
    float* q       = (float*)w;  w += rup(GG * 64 * 4);
    int*   offsets = (int*)w;    w += rup(((size_t)NN + 1) * 4);
    int4*  cnt4    = (int4*)w;   w += rup((size_t)NN * 16);
    int*   bcnt    = (int*)w;    w += rup((size_t)NBUCK * 4);
    int*   bbase   = (int*)w;    w += rup(((size_t)NBUCK + 1) * 4);
    int*   bcur    = (int*)w;    w += rup((size_t)NBUCK * 4);
    unsigned* binned = (unsigned*)w; w += rup((size_t)EE * 4);
    int*   csr     = (int*)w;    w += rup((size_t)EE * 4);
    __hip_bfloat16* W5T0 = (__hip_bfloat16*)w; w += rup((size_t)64 * 640 * 2);
    __hip_bfloat16* W5T1 = (__hip_bfloat16*)w; w += rup((size_t)128 * 640 * 2);
    __hip_bfloat16* W5T2 = (__hip_bfloat16*)w; w += rup((size_t)128 * 640 * 2);
    __hip_bfloat16* W5T3 = (__hip_bfloat16*)w; w += rup((size_t)64 * 640 * 2);
    __hip_bfloat16* xb0 = (__hip_bfloat16*)w;  w += rup((size_t)NN * 128 * 2);
    __hip_bfloat16* xb1 = (__hip_bfloat16*)w;  w += rup((size_t)NN * 128 * 2);
    __hip_bfloat16* X5  = (__hip_bfloat16*)w;  w += rup((size_t)NN * 512 * 2);

    hipMemsetAsync(bcnt, 0, (size_t)NBUCK * 4, stream);

    // fused prep: input conversion + weight transposes + question projection
    prep_all<<<PB_Q, 256, 0, stream>>>(x, xb0, qe, qn_W, qn_b, q,
                                       W0, root0, W5T0, W1, root1, W5T1,
                                       W2, root2, W5T2, W3, root3, W5T3);

    // CSR build: bucket sort
    bucket_hist<<<256, 256, 0, stream>>>(edst, bcnt);
    bucket_scan<<<1, 256, 0, stream>>>(bcnt, bbase, bcur);
    bin_edges<<<(EE + EPB - 1) / EPB, 256, 0, stream>>>(esrc, edst, eattr, bcur, binned);
    csr_fine<<<NBUCK, 256, 0, stream>>>(bbase, binned, csr, offsets, cnt4);

    int aggblk = NN / 4;                   // 12500
    int dblk = (NN + 127) / 128;           // 391

    // layer 0: xb0 -> X5 -> [h|q] xb1
    agg_x<<<aggblk, 256, 0, stream>>>(xb0, offsets, cnt4, csr, X5);
    dense5<64, 0><<<dblk, 256, 0, stream>>>(xb0, X5, W5T0, b0, q, batch, xb1, nullptr);

    // layer 1: xb1 -> X5 -> xb0
    agg_x<<<aggblk, 256, 0, stream>>>(xb1, offsets, cnt4, csr, X5);
    dense5<128, 1><<<dblk, 256, 0, stream>>>(xb1, X5, W5T1, b1, nullptr, nullptr, xb0, nullptr);

    // layer 2: xb0 -> X5 -> xb1
    agg_x<<<aggblk, 256, 0, stream>>>(xb0, offsets, cnt4, csr, X5);
    dense5<128, 1><<<dblk, 256, 0, stream>>>(xb0, X5, W5T2, b2, nullptr, nullptr, xb1, nullptr);

    // layer 3: xb1 -> X5 -> fp32 out
    agg_x<<<aggblk, 256, 0, stream>>>(xb1, offsets, cnt4, csr, X5);
    dense5<64, 2><<<dblk, 256, 0, stream>>>(xb1, X5, W5T3, b3, nullptr, nullptr, nullptr, out);
}

// Round 12
// 419.293 us; speedup vs baseline: 1.0366x; 1.0006x over previous
//
#include <hip/hip_runtime.h>
#include <hip/hip_bf16.h>

#define NN 50000
#define EE 800000
#define GG 16
#define QD 768
#define NBUCK 196      // ceil(50000/256) dst-buckets of 256 nodes
#define EPB 4000       // edges per block in bin_edges (200 blocks)

typedef __bf16 bf16x8 __attribute__((ext_vector_type(8)));
typedef float f32x4 __attribute__((ext_vector_type(4)));

static __device__ __forceinline__ float bflo(unsigned u) {
    union { unsigned v; float f; } c; c.v = u << 16; return c.f;
}
static __device__ __forceinline__ float bfhi(unsigned u) {
    union { unsigned v; float f; } c; c.v = u & 0xffff0000u; return c.f;
}

// ---------- fused prep: convert_x + 4x prep_w5 + qkern, range-dispatched ----------
// W5T[o][k], k in [0,640): k<128 -> root[k][o]; else r=(k-128)>>7 -> W[r][(k-128)&127][o]

#define PB_CVT 6250                 // NN*128/4 / 256
#define PB_W0  (PB_CVT + 160)       // 64*640/256
#define PB_W1  (PB_W0 + 320)       // 128*640/256
#define PB_W2  (PB_W1 + 320)
#define PB_W3  (PB_W2 + 160)
#define PB_Q   (PB_W3 + 4)          // 16 graphs / 4 waves

__global__ __launch_bounds__(256) void prep_all(
        const float* __restrict__ x, __hip_bfloat16* __restrict__ xb,
        const float* __restrict__ qe, const float* __restrict__ qn_W,
        const float* __restrict__ qn_b, float* __restrict__ q,
        const float* __restrict__ W0, const float* __restrict__ root0, __hip_bfloat16* __restrict__ W5T0,
        const float* __restrict__ W1, const float* __restrict__ root1, __hip_bfloat16* __restrict__ W5T1,
        const float* __restrict__ W2, const float* __restrict__ root2, __hip_bfloat16* __restrict__ W5T2,
        const float* __restrict__ W3, const float* __restrict__ root3, __hip_bfloat16* __restrict__ W5T3) {
    int blk = blockIdx.x, tid = threadIdx.x;
    if (blk < PB_CVT) {
        int i = blk * 256 + tid;              // float4 index
        float4 v = ((const float4*)x)[i];
        union { ushort4 u; __hip_bfloat16 h[4]; } o;
        o.h[0] = __float2bfloat16(v.x); o.h[1] = __float2bfloat16(v.y);
        o.h[2] = __float2bfloat16(v.z); o.h[3] = __float2bfloat16(v.w);
        ((ushort4*)xb)[i] = o.u;
    } else if (blk < PB_W3) {
        const float* W; const float* root; __hip_bfloat16* WT; int O, base;
        if (blk < PB_W0)      { W = W0; root = root0; WT = W5T0; O = 64;  base = PB_CVT; }
        else if (blk < PB_W1) { W = W1; root = root1; WT = W5T1; O = 128; base = PB_W0; }
        else if (blk < PB_W2) { W = W2; root = root2; WT = W5T2; O = 128; base = PB_W1; }
        else                  { W = W3; root = root3; WT = W5T3; O = 64;  base = PB_W2; }
        int idx = (blk - base) * 256 + tid;
        int o = idx / 640, k = idx - o * 640;
        float v;
        if (k < 128) v = root[(size_t)k * O + o];
        else { int r = (k - 128) >> 7, kk = (k - 128) & 127; v = W[((size_t)r * 128 + kk) * O + o]; }
        WT[idx] = __float2bfloat16(v);
    } else {
        int g = (blk - PB_W3) * 4 + (tid >> 6);
        int o = tid & 63;
        float s = qn_b[o];
        for (int k = 0; k < QD; ++k) s = fmaf(qe[g * QD + k], qn_W[k * 64 + o], s);
        q[g * 64 + o] = fmaxf(s, 0.f);
    }
}

// ---------- CSR build: two-level bucket sort ----------
// bucket b = dst >> 8 (256 nodes / bucket). binned entry: (src<<10)|(rel<<8)|(dst&255)

__global__ void bucket_hist(const int* __restrict__ dst, int* __restrict__ bcnt) {
    __shared__ int h[NBUCK];
    int tid = threadIdx.x;
    for (int i = tid; i < NBUCK; i += 256) h[i] = 0;
    __syncthreads();
    for (int e = blockIdx.x * 256 + tid; e < EE; e += gridDim.x * 256)
        atomicAdd(&h[dst[e] >> 8], 1);
    __syncthreads();
    for (int i = tid; i < NBUCK; i += 256) if (h[i]) atomicAdd(&bcnt[i], h[i]);
}

__global__ void bucket_scan(const int* __restrict__ bcnt, int* __restrict__ bbase,
                            int* __restrict__ bcur) {
    __shared__ int wt[4];
    int tid = threadIdx.x, lane = tid & 63, w = tid >> 6;
    int v = (tid < NBUCK) ? bcnt[tid] : 0;
    int sc = v;
#pragma unroll
    for (int off = 1; off < 64; off <<= 1) {
        int t = __shfl_up(sc, off, 64);
        if (lane >= off) sc += t;
    }
    if (lane == 63) wt[w] = sc;
    __syncthreads();
    int wbase = 0;
    for (int ww = 0; ww < w; ++ww) wbase += wt[ww];
    int excl = wbase + sc - v;
    if (tid <= NBUCK) bbase[tid] = excl;   // tid==NBUCK gets total == EE
    if (tid < NBUCK) bcur[tid] = excl;
}

// LDS-ranked binning: each block reserves contiguous runs per bucket -> dense writes
__global__ __launch_bounds__(256) void bin_edges(const int* __restrict__ src,
                                                 const int* __restrict__ dst,
                                                 const int* __restrict__ et,
                                                 int* __restrict__ bcur,
                                                 unsigned* __restrict__ binned) {
    __shared__ int lcnt[NBUCK];
    __shared__ int lbase[NBUCK];
    int tid = threadIdx.x;
    int e0 = blockIdx.x * EPB, e1 = min(e0 + EPB, EE);
    for (int base = e0; base < e1; base += 2048) {
        for (int i = tid; i < NBUCK; i += 256) lcnt[i] = 0;
        __syncthreads();
        unsigned ent[8]; int bk[8], rk[8];
#pragma unroll
        for (int k = 0; k < 8; ++k) {
            int e = base + k * 256 + tid;
            if (e < e1) {
                int d = dst[e];
                bk[k] = d >> 8;
                ent[k] = ((unsigned)src[e] << 10) | ((unsigned)et[e] << 8) | (unsigned)(d & 255);
                rk[k] = atomicAdd(&lcnt[bk[k]], 1);
            } else bk[k] = -1;
        }
        __syncthreads();
        for (int i = tid; i < NBUCK; i += 256)
            lbase[i] = lcnt[i] ? atomicAdd(&bcur[i], lcnt[i]) : 0;
        __syncthreads();
#pragma unroll
        for (int k = 0; k < 8; ++k)
            if (bk[k] >= 0) binned[lbase[bk[k]] + rk[k]] = ent[k];
        __syncthreads();
    }
}

// per-bucket fine CSR: count -> scan -> scatter in LDS; emits csr (rel-sorted per node),
// offsets, and per-(node,rel) counts cnt4
__global__ __launch_bounds__(256) void csr_fine(const int* __restrict__ bbase,
                                                const unsigned* __restrict__ binned,
                                                int* __restrict__ csr,
                                                int* __restrict__ offsets,
                                                int4* __restrict__ cnt4) {
    __shared__ int cnt[1024];   // 256 nodes x 4 rels
    __shared__ int wt[4];
    int b = blockIdx.x, tid = threadIdx.x, lane = tid & 63, w = tid >> 6;
    int seg0 = bbase[b], seg1 = bbase[b + 1];
    for (int i = tid; i < 1024; i += 256) cnt[i] = 0;
    __syncthreads();
    for (int e = seg0 + tid; e < seg1; e += 256) {
        unsigned u = binned[e];
        atomicAdd(&cnt[(u & 255) * 4 + ((u >> 8) & 3)], 1);
    }
    __syncthreads();
    int c0 = cnt[tid * 4], c1 = cnt[tid * 4 + 1], c2 = cnt[tid * 4 + 2], c3 = cnt[tid * 4 + 3];
    int s = c0 + c1 + c2 + c3;
    int sc = s;
#pragma unroll
    for (int off = 1; off < 64; off <<= 1) {
        int t = __shfl_up(sc, off, 64);
        if (lane >= off) sc += t;
    }
    if (lane == 63) wt[w] = sc;
    __syncthreads();
    int wbase = 0;
    for (int ww = 0; ww < w; ++ww) wbase += wt[ww];
    int excl = wbase + sc - s;
    cnt[tid * 4]     = excl;
    cnt[tid * 4 + 1] = excl + c0;
    cnt[tid * 4 + 2] = excl + c0 + c1;
    cnt[tid * 4 + 3] = excl + c0 + c1 + c2;
    int node = b * 256 + tid;
    if (node < NN) {
        offsets[node] = seg0 + excl;
        cnt4[node] = make_int4(c0, c1, c2, c3);
    }
    if (b == NBUCK - 1 && tid == 0) offsets[NN] = EE;
    __syncthreads();
    for (int e = seg0 + tid; e < seg1; e += 256) {
        unsigned u = binned[e];
        int r = atomicAdd(&cnt[(u & 255) * 4 + ((u >> 8) & 3)], 1);
        csr[seg0 + r] = (int)(((u >> 10) << 2) | ((u >> 8) & 3));   // (src<<2)|rel
    }
}

// ---------- agg_x: input-space aggregation, selector-FMA accumulation ----------
// X5agg[node] = [ mean_r0 (128) | mean_r1 | mean_r2 | mean_r3 ]  bf16 (512 cols)
// One wave per node, 8 gathers in flight. rel from readlane is wave-uniform ->
// selectors s_r = (r==k) computed scalar-side (s_cselect); accumulation is
// v_fmac with SGPR multiplier: 8 FMA/edge instead of 8 cndmask + 8 add.

__global__ __launch_bounds__(256) void agg_x(const __hip_bfloat16* __restrict__ X,
                                             const int* __restrict__ offsets,
                                             const int4* __restrict__ cnt4,
                                             const int* __restrict__ csr,
                                             __hip_bfloat16* __restrict__ X5agg) {
    int node = blockIdx.x * 4 + (threadIdx.x >> 6);
    int lane = threadIdx.x & 63;
    const char* xb = (const char*)X;
    int e0 = offsets[node];
    int4 c4 = cnt4[node];
    int tot = c4.x + c4.y + c4.z + c4.w;
    float a0 = 0.f, a1 = 0.f, a2 = 0.f, a3 = 0.f;   // lo halves per rel
    float h0 = 0.f, h1 = 0.f, h2 = 0.f, h3 = 0.f;   // hi halves per rel
    for (int base = 0; base < tot; base += 64) {
        int i = base + lane;
        int packed = (i < tot) ? csr[e0 + i] : 0;
        int m = min(64, tot - base);
        int j = 0;
        for (; j + 8 <= m; j += 8) {
            int p[8]; unsigned u[8];
#pragma unroll
            for (int k = 0; k < 8; ++k)
                p[k] = __builtin_amdgcn_readlane(packed, j + k);
#pragma unroll
            for (int k = 0; k < 8; ++k)
                u[k] = *(const unsigned*)(xb + (size_t)(p[k] >> 2) * 256 + lane * 4);
#pragma unroll
            for (int k = 0; k < 8; ++k) {
                int r = p[k] & 3;                    // wave-uniform (SGPR)
                float s0 = (r == 0) ? 1.f : 0.f;     // s_cselect
                float s1 = (r == 1) ? 1.f : 0.f;
                float s2 = (r == 2) ? 1.f : 0.f;
                float s3 = (r == 3) ? 1.f : 0.f;
                float lo = bflo(u[k]), hi = bfhi(u[k]);
                a0 = fmaf(s0, lo, a0); h0 = fmaf(s0, hi, h0);
                a1 = fmaf(s1, lo, a1); h1 = fmaf(s1, hi, h1);
                a2 = fmaf(s2, lo, a2); h2 = fmaf(s2, hi, h2);
                a3 = fmaf(s3, lo, a3); h3 = fmaf(s3, hi, h3);
            }
        }
        for (; j < m; ++j) {
            int p = __builtin_amdgcn_readlane(packed, j);
            unsigned u = *(const unsigned*)(xb + (size_t)(p >> 2) * 256 + lane * 4);
            int r = p & 3;
            float s0 = (r == 0) ? 1.f : 0.f;
            float s1 = (r == 1) ? 1.f : 0.f;
            float s2 = (r == 2) ? 1.f : 0.f;
            float s3 = (r == 3) ? 1.f : 0.f;
            float lo = bflo(u), hi = bfhi(u);
            a0 = fmaf(s0, lo, a0); h0 = fmaf(s0, hi, h0);
            a1 = fmaf(s1, lo, a1); h1 = fmaf(s1, hi, h1);
            a2 = fmaf(s2, lo, a2); h2 = fmaf(s2, hi, h2);
            a3 = fmaf(s3, lo, a3); h3 = fmaf(s3, hi, h3);
        }
    }
    char* x5 = (char*)X5agg;
    float iv0 = 1.f / fmaxf((float)c4.x, 1.f);
    float iv1 = 1.f / fmaxf((float)c4.y, 1.f);
    float iv2 = 1.f / fmaxf((float)c4.z, 1.f);
    float iv3 = 1.f / fmaxf((float)c4.w, 1.f);
#pragma unroll
    for (int r = 0; r < 4; ++r) {
        float lo = (r == 0) ? a0 : (r == 1) ? a1 : (r == 2) ? a2 : a3;
        float hi = (r == 0) ? h0 : (r == 1) ? h1 : (r == 2) ? h2 : h3;
        float iv = (r == 0) ? iv0 : (r == 1) ? iv1 : (r == 2) ? iv2 : iv3;
        __hip_bfloat16 g0 = __float2bfloat16(lo * iv), g1 = __float2bfloat16(hi * iv);
        ushort2 pk;
        pk.x = *(unsigned short*)&g0; pk.y = *(unsigned short*)&g1;
        *(ushort2*)(x5 + (size_t)node * 1024 + r * 256 + lane * 4) = pk;
    }
}

// ---------- dense5: out[N][O] = [Xself | X5agg] @ W5T^T + bias, fused epilogue ----------
// MODE 0: O=64, relu, write bf16 [h | q[batch]] (128 cols). MODE 1: O=128, relu bf16.
// MODE 2: O=64, no relu, fp32 to out.

template <int O, int MODE>
__global__ __launch_bounds__(256) void dense5(const __hip_bfloat16* __restrict__ Xself,
                                              const __hip_bfloat16* __restrict__ X5agg,
                                              const __hip_bfloat16* __restrict__ W5T,
                                              const float* __restrict__ bias,
                                              const float* __restrict__ q,
                                              const int* __restrict__ batch,
                                              __hip_bfloat16* __restrict__ xnext,
                                              float* __restrict__ out) {
    __shared__ char lds[16384];
    constexpr int NCT = O / 16;
    int tid = threadIdx.x;
    int wave = tid >> 6, lane = tid & 63;
    int quad = lane >> 4, l15 = lane & 15;
    int mbase = blockIdx.x * 128 + wave * 32;
    const __bf16* Ws = (const __bf16*)W5T;

    f32x4 acc[2][NCT];
#pragma unroll
    for (int mt = 0; mt < 2; ++mt)
#pragma unroll
        for (int t = 0; t < NCT; ++t) acc[mt][t] = f32x4{0, 0, 0, 0};

    int arow0 = min(mbase + l15, NN - 1);
    int arow1 = min(mbase + 16 + l15, NN - 1);
    const __bf16* aps0 = (const __bf16*)Xself + (size_t)arow0 * 128;
    const __bf16* aps1 = (const __bf16*)Xself + (size_t)arow1 * 128;
    const __bf16* apg0 = (const __bf16*)X5agg + (size_t)arow0 * 512;
    const __bf16* apg1 = (const __bf16*)X5agg + (size_t)arow1 * 512;

    for (int kc = 0; kc < 10; ++kc) {
        int k0 = kc * 64;
        const __bf16* a0base = (kc < 2) ? aps0 + kc * 64 : apg0 + (kc - 2) * 64;
        const __bf16* a1base = (kc < 2) ? aps1 + kc * 64 : apg1 + (kc - 2) * 64;
        __syncthreads();
        constexpr int NF = NCT * 2 * 64;     // fragments per chunk (512 / 1024)
#pragma unroll
        for (int i = 0; i < NF / 256; ++i) {
            int f = tid + i * 256;
            int fl = f & 63;
            int o = (f >> 7) * 16 + (fl & 15);
            int kk = k0 + ((f >> 6) & 1) * 32 + ((fl >> 4) & 3) * 8;
            *(uint4*)(lds + f * 16) = *(const uint4*)(Ws + (size_t)o * 640 + kk);
        }
        __syncthreads();
#pragma unroll
        for (int ks = 0; ks < 2; ++ks) {
            bf16x8 a0 = *(const bf16x8*)(a0base + ks * 32 + quad * 8);
            bf16x8 a1 = *(const bf16x8*)(a1base + ks * 32 + quad * 8);
#pragma unroll
            for (int t = 0; t < NCT; ++t) {
                bf16x8 b = *(const bf16x8*)(lds + ((t * 2 + ks) * 64 + lane) * 16);
                acc[0][t] = __builtin_amdgcn_mfma_f32_16x16x32_bf16(a0, b, acc[0][t], 0, 0, 0);
                acc[1][t] = __builtin_amdgcn_mfma_f32_16x16x32_bf16(a1, b, acc[1][t], 0, 0, 0);
            }
        }
    }
    __syncthreads();

    if (MODE == 2) {
#pragma unroll
        for (int mt = 0; mt < 2; ++mt)
#pragma unroll
            for (int t = 0; t < NCT; ++t) {
                int col = t * 16 + l15;
                float bv = bias[col];
#pragma unroll
                for (int reg = 0; reg < 4; ++reg) {
                    int row = mbase + mt * 16 + quad * 4 + reg;
                    if (row < NN) out[(size_t)row * 64 + col] = acc[mt][t][reg] + bv;
                }
            }
        return;
    }

    // bf16 path: per-wave LDS tile [16][128], one row-tile at a time
    __hip_bfloat16* tp = (__hip_bfloat16*)(lds + wave * 4096);
#pragma unroll
    for (int mt = 0; mt < 2; ++mt) {
        int m0 = mbase + mt * 16;
#pragma unroll
        for (int t = 0; t < NCT; ++t) {
            int col = t * 16 + l15;
            float bv = bias[col];
#pragma unroll
            for (int reg = 0; reg < 4; ++reg)
                tp[(quad * 4 + reg) * 128 + col] =
                    __float2bfloat16(fmaxf(acc[mt][t][reg] + bv, 0.f));
        }
        if (MODE == 0) {
            // fill q columns 64..127: lane -> row=lane>>2, colseg=(lane&3)*16
            int row = lane >> 2;
            int cs = (lane & 3) * 16;
            int rnode = min(m0 + row, NN - 1);
            int g = batch[rnode];
#pragma unroll
            for (int i = 0; i < 4; ++i) {
                float4 v = *(const float4*)(q + g * 64 + cs + i * 4);
                __hip_bfloat16 q0 = __float2bfloat16(v.x), q1 = __float2bfloat16(v.y);
                __hip_bfloat16 q2 = __float2bfloat16(v.z), q3 = __float2bfloat16(v.w);
                ushort4 pk;
                pk.x = *(unsigned short*)&q0; pk.y = *(unsigned short*)&q1;
                pk.z = *(unsigned short*)&q2; pk.w = *(unsigned short*)&q3;
                *(ushort4*)(tp + row * 128 + 64 + cs + i * 4) = pk;
            }
        }
        // store 16 rows x 256 B, 16B/lane coalesced
#pragma unroll
        for (int p = 0; p < 4; ++p) {
            int c = p * 64 + lane;
            int row = m0 + (c >> 4);
            if (row < NN)
                *(uint4*)((char*)xnext + (size_t)row * 256 + (c & 15) * 16) =
                    *(const uint4*)((const char*)tp + c * 16);
        }
    }
}

// ---------- launch ----------

static inline size_t rup(size_t x) { return (x + 255) & ~(size_t)255; }

extern "C" void kernel_launch(void* const* d_in, const int* in_sizes, int n_in,
                              void* d_out, int out_size, void* d_ws, size_t ws_size,
                              hipStream_t stream) {
    const float* x      = (const float*)d_in[0];
    const int*   esrc   = (const int*)d_in[1];
    const int*   edst   = esrc + EE;
    const int*   eattr  = (const int*)d_in[2];
    const int*   batch  = (const int*)d_in[3];
    const float* qe     = (const float*)d_in[4];
    const float* qn_W   = (const float*)d_in[5];
    const float* qn_b   = (const float*)d_in[6];
    const float* W0 = (const float*)d_in[7],  *root0 = (const float*)d_in[8],  *b0 = (const float*)d_in[9];
    const float* W1 = (const float*)d_in[10], *root1 = (const float*)d_in[11], *b1 = (const float*)d_in[12];
    const float* W2 = (const float*)d_in[13], *root2 = (const float*)d_in[14], *b2 = (const float*)d_in[15];
    const float* W3 = (const float*)d_in[16], *root3 = (const float*)d_in[17], *b3 = (const float*)d_in[18];
    float* out = (float*)d_out;

    char* w = (char*)d_ws;
    float* q       = (float*)w;  w += rup(GG * 64 * 4);
    int*   offsets = (int*)w;    w += rup(((size_t)NN + 1) * 4);
    int4*  cnt4    = (int4*)w;   w += rup((size_t)NN * 16);
    int*   bcnt    = (int*)w;    w += rup((size_t)NBUCK * 4);
    int*   bbase   = (int*)w;    w += rup(((size_t)NBUCK + 1) * 4);
    int*   bcur    = (int*)w;    w += rup((size_t)NBUCK * 4);
    unsigned* binned = (unsigned*)w; w += rup((size_t)EE * 4);
    int*   csr     = (int*)w;    w += rup((size_t)EE * 4);
    __hip_bfloat16* W5T0 = (__hip_bfloat16*)w; w += rup((size_t)64 * 640 * 2);
    __hip_bfloat16* W5T1 = (__hip_bfloat16*)w; w += rup((size_t)128 * 640 * 2);
    __hip_bfloat16* W5T2 = (__hip_bfloat16*)w; w += rup((size_t)128 * 640 * 2);
    __hip_bfloat16* W5T3 = (__hip_bfloat16*)w; w += rup((size_t)64 * 640 * 2);
    __hip_bfloat16* xb0 = (__hip_bfloat16*)w;  w += rup((size_t)NN * 128 * 2);
    __hip_bfloat16* xb1 = (__hip_bfloat16*)w;  w += rup((size_t)NN * 128 * 2);
    __hip_bfloat16* X5  = (__hip_bfloat16*)w;  w += rup((size_t)NN * 512 * 2);

    hipMemsetAsync(bcnt, 0, (size_t)NBUCK * 4, stream);

    // fused prep: input conversion + weight transposes + question projection
    prep_all<<<PB_Q, 256, 0, stream>>>(x, xb0, qe, qn_W, qn_b, q,
                                       W0, root0, W5T0, W1, root1, W5T1,
                                       W2, root2, W5T2, W3, root3, W5T3);

    // CSR build: bucket sort
    bucket_hist<<<256, 256, 0, stream>>>(edst, bcnt);
    bucket_scan<<<1, 256, 0, stream>>>(bcnt, bbase, bcur);
    bin_edges<<<(EE + EPB - 1) / EPB, 256, 0, stream>>>(esrc, edst, eattr, bcur, binned);
    csr_fine<<<NBUCK, 256, 0, stream>>>(bbase, binned, csr, offsets, cnt4);

    int aggblk = NN / 4;                   // 12500
    int dblk = (NN + 127) / 128;           // 391

    // layer 0: xb0 -> X5 -> [h|q] xb1
    agg_x<<<aggblk, 256, 0, stream>>>(xb0, offsets, cnt4, csr, X5);
    dense5<64, 0><<<dblk, 256, 0, stream>>>(xb0, X5, W5T0, b0, q, batch, xb1, nullptr);

    // layer 1: xb1 -> X5 -> xb0
    agg_x<<<aggblk, 256, 0, stream>>>(xb1, offsets, cnt4, csr, X5);
    dense5<128, 1><<<dblk, 256, 0, stream>>>(xb1, X5, W5T1, b1, nullptr, nullptr, xb0, nullptr);

    // layer 2: xb0 -> X5 -> xb1
    agg_x<<<aggblk, 256, 0, stream>>>(xb0, offsets, cnt4, csr, X5);
    dense5<128, 1><<<dblk, 256, 0, stream>>>(xb0, X5, W5T2, b2, nullptr, nullptr, xb1, nullptr);

    // layer 3: xb1 -> X5 -> fp32 out
    agg_x<<<aggblk, 256, 0, stream>>>(xb1, offsets, cnt4, csr, X5);
    dense5<64, 2><<<dblk, 256, 0, stream>>>(xb1, X5, W5T3, b3, nullptr, nullptr, nullptr, out);
}

// Round 13
// 417.872 us; speedup vs baseline: 1.0402x; 1.0034x over previous
//
#include <hip/hip_runtime.h>
#include <hip/hip_bf16.h>

#define NN 50000
#define EE 800000
#define GG 16
#define QD 768
#define NBUCK 196      // ceil(50000/256) dst-buckets of 256 nodes
#define EPB 4000       // edges per block in bin_edges (200 blocks)

typedef __bf16 bf16x8 __attribute__((ext_vector_type(8)));
typedef float f32x4 __attribute__((ext_vector_type(4)));

static __device__ __forceinline__ float bflo(unsigned u) {
    union { unsigned v; float f; } c; c.v = u << 16; return c.f;
}
static __device__ __forceinline__ float bfhi(unsigned u) {
    union { unsigned v; float f; } c; c.v = u & 0xffff0000u; return c.f;
}

// ---------- fused prep: convert_x + 4x prep_w5 + qkern, range-dispatched ----------
// W5T[o][k], k in [0,640): k<128 -> root[k][o]; else r=(k-128)>>7 -> W[r][(k-128)&127][o]

#define PB_CVT 6250                 // NN*128/4 / 256
#define PB_W0  (PB_CVT + 160)       // 64*640/256
#define PB_W1  (PB_W0 + 320)       // 128*640/256
#define PB_W2  (PB_W1 + 320)
#define PB_W3  (PB_W2 + 160)
#define PB_Q   (PB_W3 + 4)          // 16 graphs / 4 waves

__global__ __launch_bounds__(256) void prep_all(
        const float* __restrict__ x, __hip_bfloat16* __restrict__ xb,
        const float* __restrict__ qe, const float* __restrict__ qn_W,
        const float* __restrict__ qn_b, float* __restrict__ q,
        const float* __restrict__ W0, const float* __restrict__ root0, __hip_bfloat16* __restrict__ W5T0,
        const float* __restrict__ W1, const float* __restrict__ root1, __hip_bfloat16* __restrict__ W5T1,
        const float* __restrict__ W2, const float* __restrict__ root2, __hip_bfloat16* __restrict__ W5T2,
        const float* __restrict__ W3, const float* __restrict__ root3, __hip_bfloat16* __restrict__ W5T3) {
    int blk = blockIdx.x, tid = threadIdx.x;
    if (blk < PB_CVT) {
        int i = blk * 256 + tid;              // float4 index
        float4 v = ((const float4*)x)[i];
        union { ushort4 u; __hip_bfloat16 h[4]; } o;
        o.h[0] = __float2bfloat16(v.x); o.h[1] = __float2bfloat16(v.y);
        o.h[2] = __float2bfloat16(v.z); o.h[3] = __float2bfloat16(v.w);
        ((ushort4*)xb)[i] = o.u;
    } else if (blk < PB_W3) {
        const float* W; const float* root; __hip_bfloat16* WT; int O, base;
        if (blk < PB_W0)      { W = W0; root = root0; WT = W5T0; O = 64;  base = PB_CVT; }
        else if (blk < PB_W1) { W = W1; root = root1; WT = W5T1; O = 128; base = PB_W0; }
        else if (blk < PB_W2) { W = W2; root = root2; WT = W5T2; O = 128; base = PB_W1; }
        else                  { W = W3; root = root3; WT = W5T3; O = 64;  base = PB_W2; }
        int idx = (blk - base) * 256 + tid;
        int o = idx / 640, k = idx - o * 640;
        float v;
        if (k < 128) v = root[(size_t)k * O + o];
        else { int r = (k - 128) >> 7, kk = (k - 128) & 127; v = W[((size_t)r * 128 + kk) * O + o]; }
        WT[idx] = __float2bfloat16(v);
    } else {
        int g = (blk - PB_W3) * 4 + (tid >> 6);
        int o = tid & 63;
        float s = qn_b[o];
        for (int k = 0; k < QD; ++k) s = fmaf(qe[g * QD + k], qn_W[k * 64 + o], s);
        q[g * 64 + o] = fmaxf(s, 0.f);
    }
}

// ---------- CSR build: two-level bucket sort ----------
// bucket b = dst >> 8 (256 nodes / bucket). binned entry: (src<<10)|(rel<<8)|(dst&255)

__global__ void bucket_hist(const int* __restrict__ dst, int* __restrict__ bcnt) {
    __shared__ int h[NBUCK];
    int tid = threadIdx.x;
    for (int i = tid; i < NBUCK; i += 256) h[i] = 0;
    __syncthreads();
    for (int e = blockIdx.x * 256 + tid; e < EE; e += gridDim.x * 256)
        atomicAdd(&h[dst[e] >> 8], 1);
    __syncthreads();
    for (int i = tid; i < NBUCK; i += 256) if (h[i]) atomicAdd(&bcnt[i], h[i]);
}

__global__ void bucket_scan(const int* __restrict__ bcnt, int* __restrict__ bbase,
                            int* __restrict__ bcur) {
    __shared__ int wt[4];
    int tid = threadIdx.x, lane = tid & 63, w = tid >> 6;
    int v = (tid < NBUCK) ? bcnt[tid] : 0;
    int sc = v;
#pragma unroll
    for (int off = 1; off < 64; off <<= 1) {
        int t = __shfl_up(sc, off, 64);
        if (lane >= off) sc += t;
    }
    if (lane == 63) wt[w] = sc;
    __syncthreads();
    int wbase = 0;
    for (int ww = 0; ww < w; ++ww) wbase += wt[ww];
    int excl = wbase + sc - v;
    if (tid <= NBUCK) bbase[tid] = excl;   // tid==NBUCK gets total == EE
    if (tid < NBUCK) bcur[tid] = excl;
}

// LDS-ranked binning: each block reserves contiguous runs per bucket -> dense writes
__global__ __launch_bounds__(256) void bin_edges(const int* __restrict__ src,
                                                 const int* __restrict__ dst,
                                                 const int* __restrict__ et,
                                                 int* __restrict__ bcur,
                                                 unsigned* __restrict__ binned) {
    __shared__ int lcnt[NBUCK];
    __shared__ int lbase[NBUCK];
    int tid = threadIdx.x;
    int e0 = blockIdx.x * EPB, e1 = min(e0 + EPB, EE);
    for (int base = e0; base < e1; base += 2048) {
        for (int i = tid; i < NBUCK; i += 256) lcnt[i] = 0;
        __syncthreads();
        unsigned ent[8]; int bk[8], rk[8];
#pragma unroll
        for (int k = 0; k < 8; ++k) {
            int e = base + k * 256 + tid;
            if (e < e1) {
                int d = dst[e];
                bk[k] = d >> 8;
                ent[k] = ((unsigned)src[e] << 10) | ((unsigned)et[e] << 8) | (unsigned)(d & 255);
                rk[k] = atomicAdd(&lcnt[bk[k]], 1);
            } else bk[k] = -1;
        }
        __syncthreads();
        for (int i = tid; i < NBUCK; i += 256)
            lbase[i] = lcnt[i] ? atomicAdd(&bcur[i], lcnt[i]) : 0;
        __syncthreads();
#pragma unroll
        for (int k = 0; k < 8; ++k)
            if (bk[k] >= 0) binned[lbase[bk[k]] + rk[k]] = ent[k];
        __syncthreads();
    }
}

// per-bucket fine CSR: count -> scan -> scatter in LDS; emits csr (rel-sorted per node),
// offsets, and per-(node,rel) counts cnt4
__global__ __launch_bounds__(256) void csr_fine(const int* __restrict__ bbase,
                                                const unsigned* __restrict__ binned,
                                                int* __restrict__ csr,
                                                int* __restrict__ offsets,
                                                int4* __restrict__ cnt4) {
    __shared__ int cnt[1024];   // 256 nodes x 4 rels
    __shared__ int wt[4];
    int b = blockIdx.x, tid = threadIdx.x, lane = tid & 63, w = tid >> 6;
    int seg0 = bbase[b], seg1 = bbase[b + 1];
    for (int i = tid; i < 1024; i += 256) cnt[i] = 0;
    __syncthreads();
    for (int e = seg0 + tid; e < seg1; e += 256) {
        unsigned u = binned[e];
        atomicAdd(&cnt[(u & 255) * 4 + ((u >> 8) & 3)], 1);
    }
    __syncthreads();
    int c0 = cnt[tid * 4], c1 = cnt[tid * 4 + 1], c2 = cnt[tid * 4 + 2], c3 = cnt[tid * 4 + 3];
    int s = c0 + c1 + c2 + c3;
    int sc = s;
#pragma unroll
    for (int off = 1; off < 64; off <<= 1) {
        int t = __shfl_up(sc, off, 64);
        if (lane >= off) sc += t;
    }
    if (lane == 63) wt[w] = sc;
    __syncthreads();
    int wbase = 0;
    for (int ww = 0; ww < w; ++ww) wbase += wt[ww];
    int excl = wbase + sc - s;
    cnt[tid * 4]     = excl;
    cnt[tid * 4 + 1] = excl + c0;
    cnt[tid * 4 + 2] = excl + c0 + c1;
    cnt[tid * 4 + 3] = excl + c0 + c1 + c2;
    int node = b * 256 + tid;
    if (node < NN) {
        offsets[node] = seg0 + excl;
        cnt4[node] = make_int4(c0, c1, c2, c3);
    }
    if (b == NBUCK - 1 && tid == 0) offsets[NN] = EE;
    __syncthreads();
    for (int e = seg0 + tid; e < seg1; e += 256) {
        unsigned u = binned[e];
        int r = atomicAdd(&cnt[(u & 255) * 4 + ((u >> 8) & 3)], 1);
        csr[seg0 + r] = (int)(((u >> 10) << 2) | ((u >> 8) & 3));   // (src<<2)|rel
    }
}

// ---------- agg_x: segment-lockstep gather with zero-page masking ----------
// X5agg[node] = [ mean_r0 (128) | mean_r1 | mean_r2 | mean_r3 ]  bf16 (512 cols)
// One wave per node. The 4 rel segments advance in lockstep (fixed accumulator
// per segment -> NO per-edge select). Past-end slots load from a zeroed 256B
// page; the base-pointer choice is wave-uniform (i, c_r scalar) -> s_cselect,
// and loads are SGPR-base + loop-invariant lane*4 offset -> ~5 VALU/slot.

__global__ __launch_bounds__(256) void agg_x(const __hip_bfloat16* __restrict__ X,
                                             const int* __restrict__ offsets,
                                             const int4* __restrict__ cnt4,
                                             const int* __restrict__ csr,
                                             const float* __restrict__ zpage,
                                             __hip_bfloat16* __restrict__ X5agg) {
    int node = blockIdx.x * 4 + (threadIdx.x >> 6);
    int lane = threadIdx.x & 63;
    const char* xb = (const char*)X;
    const char* zp = (const char*)zpage;
    int e0 = offsets[node];
    int4 c4 = cnt4[node];
    int st[4];
    st[0] = 0; st[1] = c4.x; st[2] = st[1] + c4.y; st[3] = st[2] + c4.z;
    int cs[4] = {c4.x, c4.y, c4.z, c4.w};
    int maxc = max(max(cs[0], cs[1]), max(cs[2], cs[3]));
    float aL[4] = {0.f, 0.f, 0.f, 0.f}, aH[4] = {0.f, 0.f, 0.f, 0.f};
    for (int base = 0; base < maxc; base += 64) {
        int pk[4];
#pragma unroll
        for (int r = 0; r < 4; ++r)
            pk[r] = csr[min(e0 + st[r] + base + lane, EE - 1)];
        int m = min(64, maxc - base);
        for (int j = 0; j < m; j += 2) {
            const char* bp[8];
#pragma unroll
            for (int jj = 0; jj < 2; ++jj) {
                int i = base + j + jj;           // wave-uniform
#pragma unroll
                for (int r = 0; r < 4; ++r) {
                    int p = __builtin_amdgcn_readlane(pk[r], j + jj);  // SGPR
                    bp[jj * 4 + r] = (i < cs[r]) ? xb + (size_t)(p >> 2) * 256 : zp;
                }
            }
            unsigned u[8];
#pragma unroll
            for (int k = 0; k < 8; ++k)
                u[k] = *(const unsigned*)(bp[k] + lane * 4);
#pragma unroll
            for (int jj = 0; jj < 2; ++jj)
#pragma unroll
                for (int r = 0; r < 4; ++r) {
                    aL[r] += bflo(u[jj * 4 + r]);
                    aH[r] += bfhi(u[jj * 4 + r]);
                }
        }
    }
    char* x5 = (char*)X5agg;
#pragma unroll
    for (int r = 0; r < 4; ++r) {
        float iv = 1.f / fmaxf((float)cs[r], 1.f);
        __hip_bfloat16 g0 = __float2bfloat16(aL[r] * iv);
        __hip_bfloat16 g1 = __float2bfloat16(aH[r] * iv);
        ushort2 pkd;
        pkd.x = *(unsigned short*)&g0; pkd.y = *(unsigned short*)&g1;
        *(ushort2*)(x5 + (size_t)node * 1024 + r * 256 + lane * 4) = pkd;
    }
}

// ---------- dense5: out[N][O] = [Xself | X5agg] @ W5T^T + bias, fused epilogue ----------
// MODE 0: O=64, relu, write bf16 [h | q[batch]] (128 cols). MODE 1: O=128, relu bf16.
// MODE 2: O=64, no relu, fp32 to out.

template <int O, int MODE>
__global__ __launch_bounds__(256) void dense5(const __hip_bfloat16* __restrict__ Xself,
                                              const __hip_bfloat16* __restrict__ X5agg,
                                              const __hip_bfloat16* __restrict__ W5T,
                                              const float* __restrict__ bias,
                                              const float* __restrict__ q,
                                              const int* __restrict__ batch,
                                              __hip_bfloat16* __restrict__ xnext,
                                              float* __restrict__ out) {
    __shared__ char lds[16384];
    constexpr int NCT = O / 16;
    int tid = threadIdx.x;
    int wave = tid >> 6, lane = tid & 63;
    int quad = lane >> 4, l15 = lane & 15;
    int mbase = blockIdx.x * 128 + wave * 32;
    const __bf16* Ws = (const __bf16*)W5T;

    f32x4 acc[2][NCT];
#pragma unroll
    for (int mt = 0; mt < 2; ++mt)
#pragma unroll
        for (int t = 0; t < NCT; ++t) acc[mt][t] = f32x4{0, 0, 0, 0};

    int arow0 = min(mbase + l15, NN - 1);
    int arow1 = min(mbase + 16 + l15, NN - 1);
    const __bf16* aps0 = (const __bf16*)Xself + (size_t)arow0 * 128;
    const __bf16* aps1 = (const __bf16*)Xself + (size_t)arow1 * 128;
    const __bf16* apg0 = (const __bf16*)X5agg + (size_t)arow0 * 512;
    const __bf16* apg1 = (const __bf16*)X5agg + (size_t)arow1 * 512;

    for (int kc = 0; kc < 10; ++kc) {
        int k0 = kc * 64;
        const __bf16* a0base = (kc < 2) ? aps0 + kc * 64 : apg0 + (kc - 2) * 64;
        const __bf16* a1base = (kc < 2) ? aps1 + kc * 64 : apg1 + (kc - 2) * 64;
        __syncthreads();
        constexpr int NF = NCT * 2 * 64;     // fragments per chunk (512 / 1024)
#pragma unroll
        for (int i = 0; i < NF / 256; ++i) {
            int f = tid + i * 256;
            int fl = f & 63;
            int o = (f >> 7) * 16 + (fl & 15);
            int kk = k0 + ((f >> 6) & 1) * 32 + ((fl >> 4) & 3) * 8;
            *(uint4*)(lds + f * 16) = *(const uint4*)(Ws + (size_t)o * 640 + kk);
        }
        __syncthreads();
#pragma unroll
        for (int ks = 0; ks < 2; ++ks) {
            bf16x8 a0 = *(const bf16x8*)(a0base + ks * 32 + quad * 8);
            bf16x8 a1 = *(const bf16x8*)(a1base + ks * 32 + quad * 8);
#pragma unroll
            for (int t = 0; t < NCT; ++t) {
                bf16x8 b = *(const bf16x8*)(lds + ((t * 2 + ks) * 64 + lane) * 16);
                acc[0][t] = __builtin_amdgcn_mfma_f32_16x16x32_bf16(a0, b, acc[0][t], 0, 0, 0);
                acc[1][t] = __builtin_amdgcn_mfma_f32_16x16x32_bf16(a1, b, acc[1][t], 0, 0, 0);
            }
        }
    }
    __syncthreads();

    if (MODE == 2) {
#pragma unroll
        for (int mt = 0; mt < 2; ++mt)
#pragma unroll
            for (int t = 0; t < NCT; ++t) {
                int col = t * 16 + l15;
                float bv = bias[col];
#pragma unroll
                for (int reg = 0; reg < 4; ++reg) {
                    int row = mbase + mt * 16 + quad * 4 + reg;
                    if (row < NN) out[(size_t)row * 64 + col] = acc[mt][t][reg] + bv;
                }
            }
        return;
    }

    // bf16 path: per-wave LDS tile [16][128], one row-tile at a time
    __hip_bfloat16* tp = (__hip_bfloat16*)(lds + wave * 4096);
#pragma unroll
    for (int mt = 0; mt < 2; ++mt) {
        int m0 = mbase + mt * 16;
#pragma unroll
        for (int t = 0; t < NCT; ++t) {
            int col = t * 16 + l15;
            float bv = bias[col];
#pragma unroll
            for (int reg = 0; reg < 4; ++reg)
                tp[(quad * 4 + reg) * 128 + col] =
                    __float2bfloat16(fmaxf(acc[mt][t][reg] + bv, 0.f));
        }
        if (MODE == 0) {
            // fill q columns 64..127: lane -> row=lane>>2, colseg=(lane&3)*16
            int row = lane >> 2;
            int cs = (lane & 3) * 16;
            int rnode = min(m0 + row, NN - 1);
            int g = batch[rnode];
#pragma unroll
            for (int i = 0; i < 4; ++i) {
                float4 v = *(const float4*)(q + g * 64 + cs + i * 4);
                __hip_bfloat16 q0 = __float2bfloat16(v.x), q1 = __float2bfloat16(v.y);
                __hip_bfloat16 q2 = __float2bfloat16(v.z), q3 = __float2bfloat16(v.w);
                ushort4 pk;
                pk.x = *(unsigned short*)&q0; pk.y = *(unsigned short*)&q1;
                pk.z = *(unsigned short*)&q2; pk.w = *(unsigned short*)&q3;
                *(ushort4*)(tp + row * 128 + 64 + cs + i * 4) = pk;
            }
        }
        // store 16 rows x 256 B, 16B/lane coalesced
#pragma unroll
        for (int p = 0; p < 4; ++p) {
            int c = p * 64 + lane;
            int row = m0 + (c >> 4);
            if (row < NN)
                *(uint4*)((char*)xnext + (size_t)row * 256 + (c & 15) * 16) =
                    *(const uint4*)((const char*)tp + c * 16);
        }
    }
}

// ---------- launch ----------

static inline size_t rup(size_t x) { return (x + 255) & ~(size_t)255; }

extern "C" void kernel_launch(void* const* d_in, const int* in_sizes, int n_in,
                              void* d_out, int out_size, void* d_ws, size_t ws_size,
                              hipStream_t stream) {
    const float* x      = (const float*)d_in[0];
    const int*   esrc   = (const int*)d_in[1];
    const int*   edst   = esrc + EE;
    const int*   eattr  = (const int*)d_in[2];
    const int*   batch  = (const int*)d_in[3];
    const float* qe     = (const float*)d_in[4];
    const float* qn_W   = (const float*)d_in[5];
    const float* qn_b   = (const float*)d_in[6];
    const float* W0 = (const float*)d_in[7],  *root0 = (const float*)d_in[8],  *b0 = (const float*)d_in[9];
    const float* W1 = (const float*)d_in[10], *root1 = (const float*)d_in[11], *b1 = (const float*)d_in[12];
    const float* W2 = (const float*)d_in[13], *root2 = (const float*)d_in[14], *b2 = (const float*)d_in[15];
    const float* W3 = (const float*)d_in[16], *root3 = (const float*)d_in[17], *b3 = (const float*)d_in[18];
    float* out = (float*)d_out;

    char* w = (char*)d_ws;
    float* q       = (float*)w;  w += rup(GG * 64 * 4);
    float* zpage   = (float*)w;  w += rup(256);
    int*   offsets = (int*)w;    w += rup(((size_t)NN + 1) * 4);
    int4*  cnt4    = (int4*)w;   w += rup((size_t)NN * 16);
    int*   bcnt    = (int*)w;    w += rup((size_t)NBUCK * 4);
    int*   bbase   = (int*)w;    w += rup(((size_t)NBUCK + 1) * 4);
    int*   bcur    = (int*)w;    w += rup((size_t)NBUCK * 4);
    unsigned* binned = (unsigned*)w; w += rup((size_t)EE * 4);
    int*   csr     = (int*)w;    w += rup((size_t)EE * 4);
    __hip_bfloat16* W5T0 = (__hip_bfloat16*)w; w += rup((size_t)64 * 640 * 2);
    __hip_bfloat16* W5T1 = (__hip_bfloat16*)w; w += rup((size_t)128 * 640 * 2);
    __hip_bfloat16* W5T2 = (__hip_bfloat16*)w; w += rup((size_t)128 * 640 * 2);
    __hip_bfloat16* W5T3 = (__hip_bfloat16*)w; w += rup((size_t)64 * 640 * 2);
    __hip_bfloat16* xb0 = (__hip_bfloat16*)w;  w += rup((size_t)NN * 128 * 2);
    __hip_bfloat16* xb1 = (__hip_bfloat16*)w;  w += rup((size_t)NN * 128 * 2);
    __hip_bfloat16* X5  = (__hip_bfloat16*)w;  w += rup((size_t)NN * 512 * 2);

    hipMemsetAsync(bcnt, 0, (size_t)NBUCK * 4, stream);
    hipMemsetAsync(zpage, 0, 256, stream);   // zero page for masked gathers

    // fused prep: input conversion + weight transposes + question projection
    prep_all<<<PB_Q, 256, 0, stream>>>(x, xb0, qe, qn_W, qn_b, q,
                                       W0, root0, W5T0, W1, root1, W5T1,
                                       W2, root2, W5T2, W3, root3, W5T3);

    // CSR build: bucket sort
    bucket_hist<<<256, 256, 0, stream>>>(edst, bcnt);
    bucket_scan<<<1, 256, 0, stream>>>(bcnt, bbase, bcur);
    bin_edges<<<(EE + EPB - 1) / EPB, 256, 0, stream>>>(esrc, edst, eattr, bcur, binned);
    csr_fine<<<NBUCK, 256, 0, stream>>>(bbase, binned, csr, offsets, cnt4);

    int aggblk = NN / 4;                   // 12500
    int dblk = (NN + 127) / 128;           // 391

    // layer 0: xb0 -> X5 -> [h|q] xb1
    agg_x<<<aggblk, 256, 0, stream>>>(xb0, offsets, cnt4, csr, zpage, X5);
    dense5<64, 0><<<dblk, 256, 0, stream>>>(xb0, X5, W5T0, b0, q, batch, xb1, nullptr);

    // layer 1: xb1 -> X5 -> xb0
    agg_x<<<aggblk, 256, 0, stream>>>(xb1, offsets, cnt4, csr, zpage, X5);
    dense5<128, 1><<<dblk, 256, 0, stream>>>(xb1, X5, W5T1, b1, nullptr, nullptr, xb0, nullptr);

    // layer 2: xb0 -> X5 -> xb1
    agg_x<<<aggblk, 256, 0, stream>>>(xb0, offsets, cnt4, csr, zpage, X5);
    dense5<128, 1><<<dblk, 256, 0, stream>>>(xb0, X5, W5T2, b2, nullptr, nullptr, xb1, nullptr);

    // layer 3: xb1 -> X5 -> fp32 out
    agg_x<<<aggblk, 256, 0, stream>>>(xb1, offsets, cnt4, csr, zpage, X5);
    dense5<64, 2><<<dblk, 256, 0, stream>>>(xb1, X5, W5T3, b3, nullptr, nullptr, nullptr, out);
}